// Round 4
// baseline (465.094 us; speedup 1.0000x reference)
//
#include <hip/hip_runtime.h>
#include <hip/hip_bf16.h>

#define NNODES 50000
#define NEDGES 300000
#define NGRAPH 2048
#define NFEAT  128
#define NHID   256
#define DOUT   32

typedef __bf16 bf16x8 __attribute__((ext_vector_type(8)));
typedef float  f32x4  __attribute__((ext_vector_type(4)));
typedef __attribute__((address_space(1))) const void* gas_ptr;
typedef __attribute__((address_space(3))) void* las_ptr;

__device__ __forceinline__ float bf2f(unsigned short u) {
    return __uint_as_float(((unsigned)u) << 16);
}
__device__ __forceinline__ unsigned short f2bf(float f) {
    unsigned u = __float_as_uint(f);
    unsigned r = u + 0x7FFFu + ((u >> 16) & 1u);   // RNE
    return (unsigned short)(r >> 16);
}

// ---------- combined: cast x -> bf16, transpose+cast weights, zero cnt/fill ----------
__global__ __launch_bounds__(256) void prep_k(const float* __restrict__ x, unsigned short* __restrict__ x16,
                                              const float* __restrict__ W1, const float* __restrict__ W2,
                                              const float* __restrict__ W3, const float* __restrict__ Wf1,
                                              const float* __restrict__ Wf2,
                                              unsigned short* __restrict__ Wt1, unsigned short* __restrict__ Wt2,
                                              unsigned short* __restrict__ Wt3, unsigned short* __restrict__ Wf1t,
                                              unsigned short* __restrict__ Wf2t,
                                              int* __restrict__ cnt, int* __restrict__ fill) {
    int idx = blockIdx.x * 256 + threadIdx.x;
    if (idx < 800000) {                       // x cast, 8 elems/thread
        int i = idx * 8;
        float4 a = *(const float4*)&x[i];
        float4 b = *(const float4*)&x[i + 4];
        ushort4 lo = { f2bf(a.x), f2bf(a.y), f2bf(a.z), f2bf(a.w) };
        ushort4 hi = { f2bf(b.x), f2bf(b.y), f2bf(b.z), f2bf(b.w) };
        *(ushort4*)&x16[i] = lo;
        *(ushort4*)&x16[i + 4] = hi;
        return;
    }
    int t = idx - 800000;
    if (t < 200704) {                          // weight transpose: Wt[n*K+k] = W[k*N+n]
        const float* W; unsigned short* Wt; int K, N, base;
        if      (t <  32768) { W = W1;  Wt = Wt1;  K = 128; N = 256; base = 0; }
        else if (t <  98304) { W = W2;  Wt = Wt2;  K = 256; N = 256; base = 32768; }
        else if (t < 163840) { W = W3;  Wt = Wt3;  K = 256; N = 256; base = 98304; }
        else if (t < 196608) { W = Wf1; Wt = Wf1t; K = 256; N = 128; base = 163840; }
        else                 { W = Wf2; Wt = Wf2t; K = 128; N = 32;  base = 196608; }
        int i = t - base; int n = i / K, k = i - n * K;
        Wt[i] = f2bf(W[(size_t)k * N + n]);
        return;
    }
    t -= 200704;
    if (t < NNODES) { cnt[t] = 0; fill[t] = 0; }
}

__global__ __launch_bounds__(256) void edge_hist_k(const int* __restrict__ dst, int* cnt, int E) {
    int e = blockIdx.x * 256 + threadIdx.x;
    if (e < E) atomicAdd(&cnt[dst[e]], 1);
}

// block-level scan + dinv
__global__ __launch_bounds__(1024) void scan_block_k(const int* __restrict__ cnt, int* __restrict__ rowp,
                                                     int* __restrict__ part, float* __restrict__ dinv, int n) {
    __shared__ int s[1024];
    int tid = threadIdx.x;
    int i = blockIdx.x * 1024 + tid;
    int v = (i < n) ? cnt[i] : 0;
    if (i < n) dinv[i] = rsqrtf((float)(v + 1));   // +1 self-loop
    s[tid] = v;
    __syncthreads();
    for (int off = 1; off < 1024; off <<= 1) {
        int t = (tid >= off) ? s[tid - off] : 0;
        __syncthreads();
        s[tid] += t;
        __syncthreads();
    }
    if (i < n) rowp[i] = s[tid] - v;
    if (tid == 1023) part[blockIdx.x] = s[1023];
}

__global__ __launch_bounds__(64) void scan_part_k(int* part, int nb) {
    if (threadIdx.x == 0) {
        int acc = 0;
        for (int b = 0; b < nb; ++b) { int t = part[b]; part[b] = acc; acc += t; }
        part[nb] = acc;
    }
}

__global__ __launch_bounds__(256) void scan_add_k(int* __restrict__ rowp, const int* __restrict__ part,
                                                  int n, int nb) {
    int i = blockIdx.x * 256 + threadIdx.x;
    if (i < n) rowp[i] += part[i >> 10];
    else if (i == n) rowp[n] = part[nb];
}

__global__ __launch_bounds__(256) void scatter_k(const int* __restrict__ src, const int* __restrict__ dst,
                                                 const int* __restrict__ rowp, int* fill,
                                                 const float* __restrict__ dinv,
                                                 int* __restrict__ col, float* __restrict__ nrm, int E) {
    int e = blockIdx.x * 256 + threadIdx.x;
    if (e < E) {
        int s = src[e], d = dst[e];
        int p = rowp[d] + atomicAdd(&fill[d], 1);
        col[p] = s;
        nrm[p] = dinv[s] * dinv[d];
    }
}

// ---------- fused GCN layer: Out = relu( (A_hat @ X) @ Wt^T + b ), Out [M,256] bf16 ----------
// Block: 128 rows x 256 cols. Phase 1: gather-aggregate A-panel into LDS (m97 slice
// layout [K/32][128][32]). Phase 2: MFMA vs Wt staged via global_load_lds.
// LDS = K/32*8KB + 16KB: K=256 -> 80 KB -> 2 blocks/CU.
template<int K>
__global__ __launch_bounds__(256, 2) void fused_k(const unsigned short* __restrict__ X,
                                                  const unsigned short* __restrict__ Wt,  // [256][K]
                                                  const float* __restrict__ bias,
                                                  const int* __restrict__ rowp, const int* __restrict__ col,
                                                  const float* __restrict__ nrm, const float* __restrict__ dinv,
                                                  unsigned short* __restrict__ Out, int M) {
    constexpr int NS = K / 32;
    __shared__ unsigned short As[NS * 128 * 32];
    __shared__ unsigned short Bs[256 * 32];
    const int tid = threadIdx.x;
    const int lane = tid & 63;
    const int wave = tid >> 6;
    const int m = lane & 15, q = lane >> 4;
    const int rowBase = blockIdx.x * 128;

    // ---- phase 1: each wave aggregates 32 rows ----
    for (int rr = 0; rr < 32; ++rr) {
        int r = wave * 32 + rr;
        int node = rowBase + r;
        if constexpr (K == 256) {
            float4 a = make_float4(0.f, 0.f, 0.f, 0.f);
            if (node < M) {
                const ushort4* tp = (const ushort4*)X;
                float di = dinv[node]; float sw = di * di;
                ushort4 u = tp[(size_t)node * 64 + lane];
                a.x = bf2f(u.x) * sw; a.y = bf2f(u.y) * sw; a.z = bf2f(u.z) * sw; a.w = bf2f(u.w) * sw;
                int e0 = rowp[node], e1 = rowp[node + 1];
                for (int e = e0; e < e1; e += 8) {
                    int cc[8]; float w[8];
#pragma unroll
                    for (int j = 0; j < 8; ++j) {
                        int ee = e + j; bool v = ee < e1;
                        cc[j] = v ? col[ee] : 0; w[j] = v ? nrm[ee] : 0.f;
                    }
                    ushort4 mm[8];
#pragma unroll
                    for (int j = 0; j < 8; ++j) mm[j] = tp[(size_t)cc[j] * 64 + lane];
#pragma unroll
                    for (int j = 0; j < 8; ++j) {
                        a.x += bf2f(mm[j].x) * w[j]; a.y += bf2f(mm[j].y) * w[j];
                        a.z += bf2f(mm[j].z) * w[j]; a.w += bf2f(mm[j].w) * w[j];
                    }
                }
            }
            ushort4 o = { f2bf(a.x), f2bf(a.y), f2bf(a.z), f2bf(a.w) };
            *(ushort4*)&As[(lane >> 3) * 4096 + r * 32 + (lane & 7) * 4] = o;
        } else {   // K == 128: 2 feats/lane
            float ax = 0.f, ay = 0.f;
            if (node < M) {
                const ushort2* tp = (const ushort2*)X;
                float di = dinv[node]; float sw = di * di;
                ushort2 u = tp[(size_t)node * 64 + lane];
                ax = bf2f(u.x) * sw; ay = bf2f(u.y) * sw;
                int e0 = rowp[node], e1 = rowp[node + 1];
                for (int e = e0; e < e1; e += 8) {
                    int cc[8]; float w[8];
#pragma unroll
                    for (int j = 0; j < 8; ++j) {
                        int ee = e + j; bool v = ee < e1;
                        cc[j] = v ? col[ee] : 0; w[j] = v ? nrm[ee] : 0.f;
                    }
                    ushort2 mm[8];
#pragma unroll
                    for (int j = 0; j < 8; ++j) mm[j] = tp[(size_t)cc[j] * 64 + lane];
#pragma unroll
                    for (int j = 0; j < 8; ++j) { ax += bf2f(mm[j].x) * w[j]; ay += bf2f(mm[j].y) * w[j]; }
                }
            }
            ushort2 o = { f2bf(ax), f2bf(ay) };
            *(ushort2*)&As[(lane >> 4) * 4096 + r * 32 + (lane & 15) * 2] = o;
        }
    }

    // ---- phase 2: K-loop MFMA ----
    const int wr = (wave >> 1) * 64;     // row half
    const int wc = (wave & 1) * 128;     // col half
    f32x4 acc[4][8] = {};
    for (int s = 0; s < NS; ++s) {
#pragma unroll
        for (int c = 0; c < 4; ++c) {     // stage Bs slice: 256 cols x 32 k
            int u = c * 256 + tid;
            int bcol = u >> 2, part = u & 3;
            const unsigned short* g = &Wt[(size_t)bcol * K + s * 32 + part * 8];
            __builtin_amdgcn_global_load_lds((gas_ptr)g, (las_ptr)&Bs[(c * 256 + wave * 64) * 8], 16, 0, 0);
        }
        __syncthreads();   // first iter also covers phase-1 ds_writes
        bf16x8 af[4], bfr[8];
#pragma unroll
        for (int i = 0; i < 4; ++i)
            af[i] = *(const bf16x8*)&As[s * 4096 + (wr + i * 16 + m) * 32 + q * 8];
#pragma unroll
        for (int j = 0; j < 8; ++j)
            bfr[j] = *(const bf16x8*)&Bs[(wc + j * 16 + m) * 32 + q * 8];
#pragma unroll
        for (int i = 0; i < 4; ++i)
#pragma unroll
            for (int j = 0; j < 8; ++j)
                acc[i][j] = __builtin_amdgcn_mfma_f32_16x16x32_bf16(af[i], bfr[j], acc[i][j], 0, 0, 0);
        __syncthreads();
    }

    // ---- epilogue: bias + relu + bf16 store (D row = q*4+reg, col = lane&15) ----
#pragma unroll
    for (int i = 0; i < 4; ++i) {
#pragma unroll
        for (int j = 0; j < 8; ++j) {
            int cc = wc + j * 16 + m;
            float bv = bias[cc];
#pragma unroll
            for (int r4 = 0; r4 < 4; ++r4) {
                int rr2 = rowBase + wr + i * 16 + q * 4 + r4;
                if (rr2 >= M) continue;
                Out[(size_t)rr2 * 256 + cc] = f2bf(fmaxf(acc[i][j][r4] + bv, 0.f));
            }
        }
    }
}

// ---------- plain MFMA GEMM (MLP head): C[M,N] = A[M,K] @ Bt[N,K]^T ----------
// flags: bit0 relu, bit1 bias, bit2 f32 out
__global__ __launch_bounds__(256) void gemm_k(const unsigned short* __restrict__ A,
                                              const unsigned short* __restrict__ Bt,
                                              const float* __restrict__ bias, void* __restrict__ C,
                                              int M, int N, int K, int flags) {
    __shared__ unsigned short As[128 * 32];
    __shared__ unsigned short Bs[128 * 32];
    const int tid = threadIdx.x;
    const int lane = tid & 63;
    const int wave = tid >> 6;
    const int wr = (wave >> 1) * 64;
    const int wc = (wave & 1) * 64;
    const int m = lane & 15;
    const int q = lane >> 4;
    const int rowBase = blockIdx.x * 128;
    const int colBase = blockIdx.y * 128;
    const int r0  = tid >> 2;
    const int kb0 = (tid & 3) * 8;

    f32x4 acc[4][4] = {};
    for (int kt = 0; kt < K; kt += 32) {
        const unsigned short* ga0 = &A [(size_t)(rowBase + r0)      * K + kt + kb0];
        const unsigned short* ga1 = &A [(size_t)(rowBase + 64 + r0) * K + kt + kb0];
        const unsigned short* gb0 = &Bt[(size_t)(colBase + r0)      * K + kt + kb0];
        const unsigned short* gb1 = &Bt[(size_t)(colBase + 64 + r0) * K + kt + kb0];
        __builtin_amdgcn_global_load_lds((gas_ptr)ga0, (las_ptr)&As[wave * 512],        16, 0, 0);
        __builtin_amdgcn_global_load_lds((gas_ptr)ga1, (las_ptr)&As[2048 + wave * 512], 16, 0, 0);
        __builtin_amdgcn_global_load_lds((gas_ptr)gb0, (las_ptr)&Bs[wave * 512],        16, 0, 0);
        __builtin_amdgcn_global_load_lds((gas_ptr)gb1, (las_ptr)&Bs[2048 + wave * 512], 16, 0, 0);
        __syncthreads();
        bf16x8 af[4], bfr[4];
#pragma unroll
        for (int i = 0; i < 4; ++i) af[i] = *(const bf16x8*)&As[(wr + i * 16 + m) * 32 + q * 8];
#pragma unroll
        for (int j = 0; j < 4; ++j) bfr[j] = *(const bf16x8*)&Bs[(wc + j * 16 + m) * 32 + q * 8];
#pragma unroll
        for (int i = 0; i < 4; ++i)
#pragma unroll
            for (int j = 0; j < 4; ++j)
                acc[i][j] = __builtin_amdgcn_mfma_f32_16x16x32_bf16(af[i], bfr[j], acc[i][j], 0, 0, 0);
        __syncthreads();
    }
#pragma unroll
    for (int i = 0; i < 4; ++i) {
#pragma unroll
        for (int j = 0; j < 4; ++j) {
            int c = colBase + wc + j * 16 + m;
            if (c >= N) continue;
            float bv = (flags & 2) ? bias[c] : 0.f;
#pragma unroll
            for (int r = 0; r < 4; ++r) {
                int rr = rowBase + wr + i * 16 + q * 4 + r;
                if (rr >= M) continue;
                float v = acc[i][j][r] + bv;
                if (flags & 1) v = fmaxf(v, 0.f);
                if (flags & 4) ((float*)C)[(size_t)rr * N + c] = v;
                else ((unsigned short*)C)[(size_t)rr * N + c] = f2bf(v);
            }
        }
    }
}

// ---------- pooling (bounds inlined via binary search) ----------
__global__ __launch_bounds__(256) void pool_k(const unsigned short* __restrict__ h,
                                              const int* __restrict__ batch,
                                              unsigned short* __restrict__ hg, int n) {
    __shared__ float red[4][256];
    int g = blockIdx.x;
    int wave = threadIdx.x >> 6, lane = threadIdx.x & 63;
    int lo = 0, hi = n;
    while (lo < hi) { int mid = (lo + hi) >> 1; if (batch[mid] < g) lo = mid + 1; else hi = mid; }
    int s = lo;
    hi = n;
    while (lo < hi) { int mid = (lo + hi) >> 1; if (batch[mid] < g + 1) lo = mid + 1; else hi = mid; }
    int e = lo;
    const ushort4* hp = (const ushort4*)h;
    float4 acc = make_float4(0.f, 0.f, 0.f, 0.f);
    for (int i = s + wave; i < e; i += 4) {
        ushort4 v = hp[(size_t)i * 64 + lane];
        acc.x += bf2f(v.x); acc.y += bf2f(v.y); acc.z += bf2f(v.z); acc.w += bf2f(v.w);
    }
    *(float4*)&red[wave][lane * 4] = acc;
    __syncthreads();
    if (wave == 0) {
        float inv = 1.f / fmaxf((float)(e - s), 1.f);
        float v0 = red[0][lane*4+0] + red[1][lane*4+0] + red[2][lane*4+0] + red[3][lane*4+0];
        float v1 = red[0][lane*4+1] + red[1][lane*4+1] + red[2][lane*4+1] + red[3][lane*4+1];
        float v2 = red[0][lane*4+2] + red[1][lane*4+2] + red[2][lane*4+2] + red[3][lane*4+2];
        float v3 = red[0][lane*4+3] + red[1][lane*4+3] + red[2][lane*4+3] + red[3][lane*4+3];
        ushort4 o = { f2bf(v0 * inv), f2bf(v1 * inv), f2bf(v2 * inv), f2bf(v3 * inv) };
        ((ushort4*)(hg + (size_t)g * NHID))[lane] = o;
    }
}

extern "C" void kernel_launch(void* const* d_in, const int* in_sizes, int n_in,
                              void* d_out, int out_size, void* d_ws, size_t ws_size,
                              hipStream_t stream) {
    const float* x    = (const float*)d_in[0];
    const int*   ei   = (const int*)d_in[1];
    const int*   batch= (const int*)d_in[2];
    const float* W1   = (const float*)d_in[3];
    const float* b1   = (const float*)d_in[4];
    const float* W2   = (const float*)d_in[5];
    const float* b2   = (const float*)d_in[6];
    const float* W3   = (const float*)d_in[7];
    const float* b3   = (const float*)d_in[8];
    const float* Wf1  = (const float*)d_in[9];
    const float* bf1  = (const float*)d_in[10];
    const float* Wf2  = (const float*)d_in[11];
    const float* bf2  = (const float*)d_in[12];
    float* out = (float*)d_out;

    const int* e_src = ei;
    const int* e_dst = ei + NEDGES;

    char* ws = (char*)d_ws;
    size_t off = 0;
    auto alloc = [&](size_t bytes) -> void* {
        void* p = (void*)(ws + off);
        off += (bytes + 255) & ~(size_t)255;
        return p;
    };
    unsigned short* X16 = (unsigned short*)alloc((size_t)NNODES * NFEAT * 2);
    unsigned short* Ha  = (unsigned short*)alloc((size_t)NNODES * NHID * 2);
    unsigned short* Hb  = (unsigned short*)alloc((size_t)NNODES * NHID * 2);
    unsigned short* Wt1 = (unsigned short*)alloc((size_t)NHID * NFEAT * 2);
    unsigned short* Wt2 = (unsigned short*)alloc((size_t)NHID * NHID * 2);
    unsigned short* Wt3 = (unsigned short*)alloc((size_t)NHID * NHID * 2);
    unsigned short* Wf1t= (unsigned short*)alloc((size_t)NFEAT * NHID * 2);
    unsigned short* Wf2t= (unsigned short*)alloc((size_t)DOUT * NFEAT * 2);
    unsigned short* HG  = (unsigned short*)alloc((size_t)NGRAPH * NHID * 2);
    unsigned short* HR  = (unsigned short*)alloc((size_t)NGRAPH * NFEAT * 2);
    float* dinv = (float*)alloc((size_t)NNODES * 4);
    int*   cnt  = (int*)alloc((size_t)NNODES * 4);
    int*   fill = (int*)alloc((size_t)NNODES * 4);
    int*   rowp = (int*)alloc((size_t)(NNODES + 1) * 4);
    int*   col  = (int*)alloc((size_t)NEDGES * 4);
    float* nrm  = (float*)alloc((size_t)NEDGES * 4);
    int*   part = (int*)alloc((size_t)64 * 4);
    (void)alloc(65536);   // tail pad: keeps gemm_k tile over-reads inside d_ws

    const int nb = (NNODES + 1023) / 1024;   // 49

    // ---- prep: casts + zero cnt/fill (1 launch) ----
    hipLaunchKernelGGL(prep_k, dim3((1050704 + 255) / 256), dim3(256), 0, stream,
                       x, X16, W1, W2, W3, Wf1, Wf2, Wt1, Wt2, Wt3, Wf1t, Wf2t, cnt, fill);
    // ---- CSR + norm ----
    hipLaunchKernelGGL(edge_hist_k, dim3((NEDGES + 255) / 256), dim3(256), 0, stream, e_dst, cnt, NEDGES);
    hipLaunchKernelGGL(scan_block_k, dim3(nb), dim3(1024), 0, stream, cnt, rowp, part, dinv, NNODES);
    hipLaunchKernelGGL(scan_part_k, dim3(1), dim3(64), 0, stream, part, nb);
    hipLaunchKernelGGL(scan_add_k, dim3((NNODES + 1 + 255) / 256), dim3(256), 0, stream, rowp, part, NNODES, nb);
    hipLaunchKernelGGL(scatter_k, dim3((NEDGES + 255) / 256), dim3(256), 0, stream,
                       e_src, e_dst, rowp, fill, dinv, col, nrm, NEDGES);

    // ---- 3 fused GCN layers ----
    const int ng = (NNODES + 127) / 128;   // 391
    hipLaunchKernelGGL((fused_k<128>), dim3(ng), dim3(256), 0, stream,
                       X16, Wt1, b1, rowp, col, nrm, dinv, Ha, NNODES);
    hipLaunchKernelGGL((fused_k<256>), dim3(ng), dim3(256), 0, stream,
                       Ha, Wt2, b2, rowp, col, nrm, dinv, Hb, NNODES);
    hipLaunchKernelGGL((fused_k<256>), dim3(ng), dim3(256), 0, stream,
                       Hb, Wt3, b3, rowp, col, nrm, dinv, Ha, NNODES);

    // ---- pool ----
    hipLaunchKernelGGL(pool_k, dim3(NGRAPH), dim3(256), 0, stream, Ha, batch, HG, NNODES);

    // ---- MLP head ----
    hipLaunchKernelGGL(gemm_k, dim3(NGRAPH / 128, 1), dim3(256), 0, stream,
                       HG, Wf1t, bf1, HR, NGRAPH, NFEAT, NHID, 3);
    hipLaunchKernelGGL(gemm_k, dim3(NGRAPH / 128, 1), dim3(256), 0, stream,
                       HR, Wf2t, bf2, out, NGRAPH, DOUT, NFEAT, 6);
}

// Round 5
// 388.284 us; speedup vs baseline: 1.1978x; 1.1978x over previous
//
#include <hip/hip_runtime.h>
#include <hip/hip_bf16.h>

#define NNODES 50000
#define NEDGES 300000
#define NGRAPH 2048
#define NFEAT  128
#define NHID   256
#define DOUT   32

typedef __bf16 bf16x8 __attribute__((ext_vector_type(8)));
typedef float  f32x4  __attribute__((ext_vector_type(4)));
typedef __attribute__((address_space(1))) const void* gas_ptr;
typedef __attribute__((address_space(3))) void* las_ptr;

__device__ __forceinline__ float bf2f(unsigned short u) {
    return __uint_as_float(((unsigned)u) << 16);
}
__device__ __forceinline__ unsigned short f2bf(float f) {
    unsigned u = __float_as_uint(f);
    unsigned r = u + 0x7FFFu + ((u >> 16) & 1u);   // RNE
    return (unsigned short)(r >> 16);
}

// ---------- prep: cast x -> bf16, transpose+cast weights, zero cnt/fill ----------
__global__ __launch_bounds__(256) void prep_k(const float* __restrict__ x, unsigned short* __restrict__ x16,
                                              const float* __restrict__ W1, const float* __restrict__ W2,
                                              const float* __restrict__ W3, const float* __restrict__ Wf1,
                                              const float* __restrict__ Wf2,
                                              unsigned short* __restrict__ Wt1, unsigned short* __restrict__ Wt2,
                                              unsigned short* __restrict__ Wt3, unsigned short* __restrict__ Wf1t,
                                              unsigned short* __restrict__ Wf2t,
                                              int* __restrict__ cnt, int* __restrict__ fill) {
    int idx = blockIdx.x * 256 + threadIdx.x;
    if (idx < 800000) {                       // x cast, 8 elems/thread
        int i = idx * 8;
        float4 a = *(const float4*)&x[i];
        float4 b = *(const float4*)&x[i + 4];
        ushort4 lo = { f2bf(a.x), f2bf(a.y), f2bf(a.z), f2bf(a.w) };
        ushort4 hi = { f2bf(b.x), f2bf(b.y), f2bf(b.z), f2bf(b.w) };
        *(ushort4*)&x16[i] = lo;
        *(ushort4*)&x16[i + 4] = hi;
        return;
    }
    int t = idx - 800000;
    if (t < 200704) {                          // weight transpose: Wt[n*K+k] = W[k*N+n]
        const float* W; unsigned short* Wt; int K, N, base;
        if      (t <  32768) { W = W1;  Wt = Wt1;  K = 128; N = 256; base = 0; }
        else if (t <  98304) { W = W2;  Wt = Wt2;  K = 256; N = 256; base = 32768; }
        else if (t < 163840) { W = W3;  Wt = Wt3;  K = 256; N = 256; base = 98304; }
        else if (t < 196608) { W = Wf1; Wt = Wf1t; K = 256; N = 128; base = 163840; }
        else                 { W = Wf2; Wt = Wf2t; K = 128; N = 32;  base = 196608; }
        int i = t - base; int n = i / K, k = i - n * K;
        Wt[i] = f2bf(W[(size_t)k * N + n]);
        return;
    }
    t -= 200704;
    if (t < NNODES) { cnt[t] = 0; fill[t] = 0; }
}

__global__ __launch_bounds__(256) void edge_hist_k(const int* __restrict__ dst, int* cnt, int E) {
    int e = blockIdx.x * 256 + threadIdx.x;
    if (e < E) atomicAdd(&cnt[dst[e]], 1);
}

// block-level scan + dinv
__global__ __launch_bounds__(1024) void scan_block_k(const int* __restrict__ cnt, int* __restrict__ rowp,
                                                     int* __restrict__ part, float* __restrict__ dinv, int n) {
    __shared__ int s[1024];
    int tid = threadIdx.x;
    int i = blockIdx.x * 1024 + tid;
    int v = (i < n) ? cnt[i] : 0;
    if (i < n) dinv[i] = rsqrtf((float)(v + 1));   // +1 self-loop
    s[tid] = v;
    __syncthreads();
    for (int off = 1; off < 1024; off <<= 1) {
        int t = (tid >= off) ? s[tid - off] : 0;
        __syncthreads();
        s[tid] += t;
        __syncthreads();
    }
    if (i < n) rowp[i] = s[tid] - v;
    if (tid == 1023) part[blockIdx.x] = s[1023];
}

// add block offsets (each block redundantly scans the 49 partials — cheap)
__global__ __launch_bounds__(256) void scan_add_k(int* __restrict__ rowp, const int* __restrict__ part,
                                                  int n, int nb) {
    __shared__ int pp[64];
    int tid = threadIdx.x;
    if (tid == 0) {
        int acc = 0;
        for (int b = 0; b < nb; ++b) { pp[b] = acc; acc += part[b]; }
        pp[nb] = acc;
    }
    __syncthreads();
    int i = blockIdx.x * 256 + tid;
    if (i < n) rowp[i] += pp[i >> 10];
    else if (i == n) rowp[n] = pp[nb];
}

__global__ __launch_bounds__(256) void scatter_k(const int* __restrict__ src, const int* __restrict__ dst,
                                                 const int* __restrict__ rowp, int* fill,
                                                 const float* __restrict__ dinv,
                                                 int* __restrict__ col, float* __restrict__ nrm, int E) {
    int e = blockIdx.x * 256 + threadIdx.x;
    if (e < E) {
        int s = src[e], d = dst[e];
        int p = rowp[d] + atomicAdd(&fill[d], 1);
        col[p] = s;
        nrm[p] = dinv[s] * dinv[d];
    }
}

// ---------- MFMA GEMM, BM=64 x BN=256: C[M,N] = A[M,K] @ Bt[N,K]^T ----------
// flags: bit0 relu, bit1 bias, bit2 f32 out. K % 32 == 0. Over-reads A-rows >= M
// and Bt-rows >= N (stays in d_ws; results never stored).
__global__ __launch_bounds__(256) void gemm_k(const unsigned short* __restrict__ A,
                                              const unsigned short* __restrict__ Bt,
                                              const float* __restrict__ bias, void* __restrict__ C,
                                              int M, int N, int K, int flags) {
    __shared__ unsigned short As[64 * 32];     // 4 KB
    __shared__ unsigned short Bs[256 * 32];    // 16 KB
    const int tid = threadIdx.x;
    const int lane = tid & 63;
    const int wave = tid >> 6;
    const int m = lane & 15, q = lane >> 4;
    const int wr = (wave & 1) * 32;            // wave row offset (2 tiles of 16)
    const int wc = (wave >> 1) * 128;          // wave col offset (8 tiles of 16)
    const int rowBase = blockIdx.x * 64;
    const int ar = tid >> 2, ak = (tid & 3) * 8;

    f32x4 acc[2][8] = {};
    for (int kt = 0; kt < K; kt += 32) {
        const unsigned short* ga = &A[(size_t)(rowBase + ar) * K + kt + ak];
        __builtin_amdgcn_global_load_lds((gas_ptr)ga, (las_ptr)&As[wave * 512], 16, 0, 0);
#pragma unroll
        for (int c2 = 0; c2 < 4; ++c2) {
            int u = c2 * 256 + tid;
            int bcol = u >> 2, kp = u & 3;
            const unsigned short* gb = &Bt[(size_t)bcol * K + kt + kp * 8];
            __builtin_amdgcn_global_load_lds((gas_ptr)gb, (las_ptr)&Bs[(c2 * 256 + wave * 64) * 8], 16, 0, 0);
        }
        __syncthreads();
        bf16x8 af[2], bfr[8];
#pragma unroll
        for (int i = 0; i < 2; ++i) af[i] = *(const bf16x8*)&As[(wr + i * 16 + m) * 32 + q * 8];
#pragma unroll
        for (int j = 0; j < 8; ++j) bfr[j] = *(const bf16x8*)&Bs[(wc + j * 16 + m) * 32 + q * 8];
#pragma unroll
        for (int i = 0; i < 2; ++i)
#pragma unroll
            for (int j = 0; j < 8; ++j)
                acc[i][j] = __builtin_amdgcn_mfma_f32_16x16x32_bf16(af[i], bfr[j], acc[i][j], 0, 0, 0);
        __syncthreads();
    }
    // epilogue: D row = q*4+reg, col = lane&15 (m89-verified)
#pragma unroll
    for (int i = 0; i < 2; ++i) {
#pragma unroll
        for (int j = 0; j < 8; ++j) {
            int c = wc + j * 16 + m;
            if (c >= N) continue;
            float bv = (flags & 2) ? bias[c] : 0.f;
#pragma unroll
            for (int r = 0; r < 4; ++r) {
                int rr = rowBase + wr + i * 16 + q * 4 + r;
                if (rr >= M) continue;
                float v = acc[i][j][r] + bv;
                if (flags & 1) v = fmaxf(v, 0.f);
                if (flags & 4) ((float*)C)[(size_t)rr * N + c] = v;
                else ((unsigned short*)C)[(size_t)rr * N + c] = f2bf(v);
            }
        }
    }
}

// ---------- aggregation: 2 nodes/wave, interleaved 4+4 edge batches ----------
__global__ __launch_bounds__(256) void agg_k(const unsigned short* __restrict__ t,
                                             const int* __restrict__ rowp, const int* __restrict__ col,
                                             const float* __restrict__ nrm, const float* __restrict__ dinv,
                                             const float* __restrict__ bias,
                                             unsigned short* __restrict__ h, int n) {
    int wave = threadIdx.x >> 6;
    int lane = threadIdx.x & 63;
    int n0 = (blockIdx.x * 4 + wave) * 2;
    if (n0 >= n) return;
    int n1 = n0 + 1;
    bool has1 = n1 < n;
    const ushort4* tp = (const ushort4*)t;
    float di0 = dinv[n0], sw0 = di0 * di0;
    float di1 = has1 ? dinv[n1] : 0.f, sw1 = di1 * di1;
    ushort4 u0 = tp[(size_t)n0 * 64 + lane];
    ushort4 u1 = tp[(size_t)(has1 ? n1 : n0) * 64 + lane];
    float a0x = bf2f(u0.x) * sw0, a0y = bf2f(u0.y) * sw0, a0z = bf2f(u0.z) * sw0, a0w = bf2f(u0.w) * sw0;
    float a1x = bf2f(u1.x) * sw1, a1y = bf2f(u1.y) * sw1, a1z = bf2f(u1.z) * sw1, a1w = bf2f(u1.w) * sw1;
    int i0 = rowp[n0], e0 = rowp[n0 + 1];
    int i1 = e0, e1 = has1 ? rowp[n1 + 1] : e0;   // CSR contiguity: rowp[n1] == rowp[n0+1]
    while (i0 < e0 || i1 < e1) {
        int c[8]; float w[8];
#pragma unroll
        for (int j = 0; j < 4; ++j) {
            bool v = i0 + j < e0;
            c[j] = v ? col[i0 + j] : 0; w[j] = v ? nrm[i0 + j] : 0.f;
        }
#pragma unroll
        for (int j = 0; j < 4; ++j) {
            bool v = i1 + j < e1;
            c[4 + j] = v ? col[i1 + j] : 0; w[4 + j] = v ? nrm[i1 + j] : 0.f;
        }
        ushort4 mm[8];
#pragma unroll
        for (int j = 0; j < 8; ++j) mm[j] = tp[(size_t)c[j] * 64 + lane];
#pragma unroll
        for (int j = 0; j < 4; ++j) {
            a0x += bf2f(mm[j].x) * w[j]; a0y += bf2f(mm[j].y) * w[j];
            a0z += bf2f(mm[j].z) * w[j]; a0w += bf2f(mm[j].w) * w[j];
        }
#pragma unroll
        for (int j = 0; j < 4; ++j) {
            a1x += bf2f(mm[4 + j].x) * w[4 + j]; a1y += bf2f(mm[4 + j].y) * w[4 + j];
            a1z += bf2f(mm[4 + j].z) * w[4 + j]; a1w += bf2f(mm[4 + j].w) * w[4 + j];
        }
        i0 += 4; i1 += 4;
    }
    float4 b4 = *(const float4*)&bias[lane * 4];
    ushort4 o0 = { f2bf(fmaxf(a0x + b4.x, 0.f)), f2bf(fmaxf(a0y + b4.y, 0.f)),
                   f2bf(fmaxf(a0z + b4.z, 0.f)), f2bf(fmaxf(a0w + b4.w, 0.f)) };
    ((ushort4*)(h + (size_t)n0 * NHID))[lane] = o0;
    if (has1) {
        ushort4 o1 = { f2bf(fmaxf(a1x + b4.x, 0.f)), f2bf(fmaxf(a1y + b4.y, 0.f)),
                       f2bf(fmaxf(a1z + b4.z, 0.f)), f2bf(fmaxf(a1w + b4.w, 0.f)) };
        ((ushort4*)(h + (size_t)n1 * NHID))[lane] = o1;
    }
}

// ---------- pooling (bounds via binary search) ----------
__global__ __launch_bounds__(256) void pool_k(const unsigned short* __restrict__ h,
                                              const int* __restrict__ batch,
                                              unsigned short* __restrict__ hg, int n) {
    __shared__ float red[4][256];
    int g = blockIdx.x;
    int wave = threadIdx.x >> 6, lane = threadIdx.x & 63;
    int lo = 0, hi = n;
    while (lo < hi) { int mid = (lo + hi) >> 1; if (batch[mid] < g) lo = mid + 1; else hi = mid; }
    int s = lo;
    hi = n;
    while (lo < hi) { int mid = (lo + hi) >> 1; if (batch[mid] < g + 1) lo = mid + 1; else hi = mid; }
    int e = lo;
    const ushort4* hp = (const ushort4*)h;
    float4 acc = make_float4(0.f, 0.f, 0.f, 0.f);
    for (int i = s + wave; i < e; i += 4) {
        ushort4 v = hp[(size_t)i * 64 + lane];
        acc.x += bf2f(v.x); acc.y += bf2f(v.y); acc.z += bf2f(v.z); acc.w += bf2f(v.w);
    }
    *(float4*)&red[wave][lane * 4] = acc;
    __syncthreads();
    if (wave == 0) {
        float inv = 1.f / fmaxf((float)(e - s), 1.f);
        float v0 = red[0][lane*4+0] + red[1][lane*4+0] + red[2][lane*4+0] + red[3][lane*4+0];
        float v1 = red[0][lane*4+1] + red[1][lane*4+1] + red[2][lane*4+1] + red[3][lane*4+1];
        float v2 = red[0][lane*4+2] + red[1][lane*4+2] + red[2][lane*4+2] + red[3][lane*4+2];
        float v3 = red[0][lane*4+3] + red[1][lane*4+3] + red[2][lane*4+3] + red[3][lane*4+3];
        ushort4 o = { f2bf(v0 * inv), f2bf(v1 * inv), f2bf(v2 * inv), f2bf(v3 * inv) };
        ((ushort4*)(hg + (size_t)g * NHID))[lane] = o;
    }
}

extern "C" void kernel_launch(void* const* d_in, const int* in_sizes, int n_in,
                              void* d_out, int out_size, void* d_ws, size_t ws_size,
                              hipStream_t stream) {
    const float* x    = (const float*)d_in[0];
    const int*   ei   = (const int*)d_in[1];
    const int*   batch= (const int*)d_in[2];
    const float* W1   = (const float*)d_in[3];
    const float* b1   = (const float*)d_in[4];
    const float* W2   = (const float*)d_in[5];
    const float* b2   = (const float*)d_in[6];
    const float* W3   = (const float*)d_in[7];
    const float* b3   = (const float*)d_in[8];
    const float* Wf1  = (const float*)d_in[9];
    const float* bf1  = (const float*)d_in[10];
    const float* Wf2  = (const float*)d_in[11];
    const float* bf2  = (const float*)d_in[12];
    float* out = (float*)d_out;

    const int* e_src = ei;
    const int* e_dst = ei + NEDGES;

    char* ws = (char*)d_ws;
    size_t off = 0;
    auto alloc = [&](size_t bytes) -> void* {
        void* p = (void*)(ws + off);
        off += (bytes + 255) & ~(size_t)255;
        return p;
    };
    unsigned short* X16 = (unsigned short*)alloc((size_t)NNODES * NFEAT * 2);
    unsigned short* Ta  = (unsigned short*)alloc((size_t)NNODES * NHID * 2);
    unsigned short* Tb  = (unsigned short*)alloc((size_t)NNODES * NHID * 2);
    unsigned short* Wt1 = (unsigned short*)alloc((size_t)NHID * NFEAT * 2);
    unsigned short* Wt2 = (unsigned short*)alloc((size_t)NHID * NHID * 2);
    unsigned short* Wt3 = (unsigned short*)alloc((size_t)NHID * NHID * 2);
    unsigned short* Wf1t= (unsigned short*)alloc((size_t)NFEAT * NHID * 2);
    unsigned short* Wf2t= (unsigned short*)alloc((size_t)DOUT * NFEAT * 2);
    unsigned short* HG  = (unsigned short*)alloc((size_t)NGRAPH * NHID * 2);
    unsigned short* HR  = (unsigned short*)alloc((size_t)NGRAPH * NFEAT * 2);
    float* dinv = (float*)alloc((size_t)NNODES * 4);
    int*   cnt  = (int*)alloc((size_t)NNODES * 4);
    int*   fill = (int*)alloc((size_t)NNODES * 4);
    int*   rowp = (int*)alloc((size_t)(NNODES + 1) * 4);
    int*   col  = (int*)alloc((size_t)NEDGES * 4);
    float* nrm  = (float*)alloc((size_t)NEDGES * 4);
    int*   part = (int*)alloc((size_t)64 * 4);
    (void)alloc(131072);   // tail pad: keeps GEMM tile over-reads inside d_ws

    const int nb = (NNODES + 1023) / 1024;   // 49

    // ---- prep: casts + zero cnt/fill ----
    hipLaunchKernelGGL(prep_k, dim3((1050704 + 255) / 256), dim3(256), 0, stream,
                       x, X16, W1, W2, W3, Wf1, Wf2, Wt1, Wt2, Wt3, Wf1t, Wf2t, cnt, fill);
    // ---- CSR + norm ----
    hipLaunchKernelGGL(edge_hist_k, dim3((NEDGES + 255) / 256), dim3(256), 0, stream, e_dst, cnt, NEDGES);
    hipLaunchKernelGGL(scan_block_k, dim3(nb), dim3(1024), 0, stream, cnt, rowp, part, dinv, NNODES);
    hipLaunchKernelGGL(scan_add_k, dim3((NNODES + 1 + 255) / 256), dim3(256), 0, stream, rowp, part, NNODES, nb);
    hipLaunchKernelGGL(scatter_k, dim3((NEDGES + 255) / 256), dim3(256), 0, stream,
                       e_src, e_dst, rowp, fill, dinv, col, nrm, NEDGES);

    const int ngemm = (NNODES + 63) / 64;    // 782
    const int nagg  = (NNODES / 2 + 3) / 4;  // 6250
    // ---- layer 1 ----
    hipLaunchKernelGGL(gemm_k, dim3(ngemm), dim3(256), 0, stream,
                       X16, Wt1, (const float*)nullptr, Ta, NNODES, NHID, NFEAT, 0);
    hipLaunchKernelGGL(agg_k, dim3(nagg), dim3(256), 0, stream,
                       Ta, rowp, col, nrm, dinv, b1, Tb, NNODES);
    // ---- layer 2 ----
    hipLaunchKernelGGL(gemm_k, dim3(ngemm), dim3(256), 0, stream,
                       Tb, Wt2, (const float*)nullptr, Ta, NNODES, NHID, NHID, 0);
    hipLaunchKernelGGL(agg_k, dim3(nagg), dim3(256), 0, stream,
                       Ta, rowp, col, nrm, dinv, b2, Tb, NNODES);
    // ---- layer 3 ----
    hipLaunchKernelGGL(gemm_k, dim3(ngemm), dim3(256), 0, stream,
                       Tb, Wt3, (const float*)nullptr, Ta, NNODES, NHID, NHID, 0);
    hipLaunchKernelGGL(agg_k, dim3(nagg), dim3(256), 0, stream,
                       Ta, rowp, col, nrm, dinv, b3, Tb, NNODES);

    // ---- pool ----
    hipLaunchKernelGGL(pool_k, dim3(NGRAPH), dim3(256), 0, stream, Tb, batch, HG, NNODES);

    // ---- MLP head ----
    hipLaunchKernelGGL(gemm_k, dim3((NGRAPH + 63) / 64), dim3(256), 0, stream,
                       HG, Wf1t, bf1, HR, NGRAPH, NFEAT, NHID, 3);
    hipLaunchKernelGGL(gemm_k, dim3((NGRAPH + 63) / 64), dim3(256), 0, stream,
                       HR, Wf2t, bf2, out, NGRAPH, DOUT, NFEAT, 6);
}